// Round 12
// baseline (224.471 us; speedup 1.0000x reference)
//
#include <hip/hip_runtime.h>
#include <cstdint>
#include <cstddef>

#define EMBED 1024
#define NHEAD 16
#define HD    64
#define BATCH 2
#define SEQ   2048
#define MROWS (BATCH*SEQ)   // 4096
#define QSCALE 0.1803368801111137f   // log2(e)/8

typedef __bf16 bf16;
typedef __bf16 bf16x8 __attribute__((ext_vector_type(8)));
typedef float  f32x4  __attribute__((ext_vector_type(4)));
typedef unsigned int u32;

#if __has_builtin(__builtin_amdgcn_exp2f)
#define EXP2(x) __builtin_amdgcn_exp2f(x)
#else
#define EXP2(x) exp2f(x)
#endif

typedef const u32 __attribute__((address_space(1)))* gp_t;
typedef u32 __attribute__((address_space(3)))* lp_t;

// async global->LDS, 16B/lane; LDS dest = wave-uniform base + lane*16
__device__ __forceinline__ void g2l16(const void* g, void* l) {
  __builtin_amdgcn_global_load_lds((gp_t)(uintptr_t)g, (lp_t)(u32)(uintptr_t)l, 16, 0, 0);
}

#define MFMA(a, b, c) __builtin_amdgcn_mfma_f32_16x16x32_bf16((a), (b), (c), 0, 0, 0)

// ---------------- all casts fp32 -> bf16, one dispatch ----------------
#define SZX8 ((MROWS*EMBED)/8)   // 524288
#define SZW8 ((EMBED*EMBED)/8)   // 131072

__global__ void cast_all(const float* __restrict__ q, const float* __restrict__ k,
                         const float* __restrict__ v, const float* __restrict__ wq,
                         const float* __restrict__ wk, const float* __restrict__ wv,
                         const float* __restrict__ wo,
                         bf16* xq, bf16* xk, bf16* xv,
                         bf16* wqb, bf16* wkb, bf16* wvb, bf16* wob) {
  int z = blockIdx.y;
  const float* in; bf16* out;
  switch (z) {
    case 0: in = q;  out = xq;  break;
    case 1: in = k;  out = xk;  break;
    case 2: in = v;  out = xv;  break;
    case 3: in = wq; out = wqb; break;
    case 4: in = wk; out = wkb; break;
    case 5: in = wv; out = wvb; break;
    default: in = wo; out = wob; break;
  }
  int n8 = (z < 3) ? SZX8 : SZW8;
  int i = blockIdx.x * blockDim.x + threadIdx.x;
  if (i >= n8) return;
  const float4* p = (const float4*)in;
  float4 a = p[2*i], b = p[2*i+1];
  union { bf16 h[8]; uint4 u; } r;
  r.h[0] = (bf16)a.x; r.h[1] = (bf16)a.y; r.h[2] = (bf16)a.z; r.h[3] = (bf16)a.w;
  r.h[4] = (bf16)b.x; r.h[5] = (bf16)b.y; r.h[6] = (bf16)b.z; r.h[7] = (bf16)b.w;
  ((uint4*)out)[i] = r.u;
}

// ---------------- GEMM core 128x128: C = A @ B^T ----------------------
// v7 (verified r7): DEPTH-2 counted-vmcnt pipeline, triple-buffer LDS.
#define BM 128
#define BN 128
#define BK 32
#define NKI (EMBED/BK)   // 32

__device__ __forceinline__ void gemm_core(
    const bf16* __restrict__ A, const bf16* __restrict__ W,
    int m0, int n0, bf16* Al, bf16* Bl, f32x4 (&acc)[4][4])
{
  const int tid  = threadIdx.x;
  const int lane = tid & 63, wid = tid >> 6;
  const int quad = lane >> 4, l16 = lane & 15;
  const int wm = wid >> 1, wn = wid & 1;

  const int R = tid >> 2, Cc = tid & 3;
  const int gcol = (Cc ^ ((R >> 1) & 3)) * 8;          // swizzled source column
  const bf16* Ag = A + (size_t)(m0 + R) * EMBED + gcol;
  const bf16* Bg = W + (size_t)(n0 + R) * EMBED + gcol;
  bf16* AlW = Al + wid * 512;                          // wave's 1KB chunk
  bf16* BlW = Bl + wid * 512;

#define GSTAGE(ki) do { \
    const int nb_ = (ki) % 3; const int k0_ = (ki) * BK; \
    g2l16(Ag + k0_,                    AlW + nb_*4096); \
    g2l16(Ag + (size_t)64*EMBED + k0_, AlW + nb_*4096 + 2048); \
    g2l16(Bg + k0_,                    BlW + nb_*4096); \
    g2l16(Bg + (size_t)64*EMBED + k0_, BlW + nb_*4096 + 2048); } while (0)

  GSTAGE(0);
  GSTAGE(1);                            // 8 loads in flight

  for (int ki = 0; ki < NKI; ++ki) {
    if (ki < NKI - 1) asm volatile("s_waitcnt vmcnt(4)" ::: "memory");
    else              asm volatile("s_waitcnt vmcnt(0)" ::: "memory");
    __builtin_amdgcn_s_barrier();
    __builtin_amdgcn_sched_barrier(0);
    if (ki + 2 < NKI) GSTAGE(ki + 2);   // in flight across 2 compute phases

    const bf16* Ac = Al + (ki % 3)*4096;
    const bf16* Bc = Bl + (ki % 3)*4096;
    bf16x8 af[4], bg[4];
#pragma unroll
    for (int i = 0; i < 4; ++i) {
      int ra = wm*64 + i*16 + l16;
      af[i] = *(const bf16x8*)(Ac + ra*32 + ((quad ^ ((ra>>1)&3))*8));
      int rb = wn*64 + i*16 + l16;
      bg[i] = *(const bf16x8*)(Bc + rb*32 + ((quad ^ ((rb>>1)&3))*8));
    }
#pragma unroll
    for (int i = 0; i < 4; ++i)
#pragma unroll
      for (int j = 0; j < 4; ++j)
        acc[i][j] = MFMA(af[i], bg[j], acc[i][j]);
    // no end-of-iteration barrier: next top's {vmcnt; s_barrier} covers it
  }
#undef GSTAGE
}

// QKV fused: work-index selects {Q,K,V}. Q scaled by log2(e)/8.
// z==2 computes V^T DIRECTLY: C[dim][token] = Wv @ Xv^T, stored permuted
// per 64-token tile for the key-half-split attn PV A-fragment:
//   token loc = g*16 + quad*4 + r  ->  pos = (g>>1)*32 + quad*8 + r*2 + (g&1)
// XCD swizzle (verified r7): hw%8 = XCD; XCD k owns contiguous range.
__global__ __launch_bounds__(256) void qkv_kernel(
    const bf16* __restrict__ Xq, const bf16* __restrict__ Xk, const bf16* __restrict__ Xv,
    const bf16* __restrict__ Wq, const bf16* __restrict__ Wk, const bf16* __restrict__ Wv,
    const float* __restrict__ bq, const float* __restrict__ bk, const float* __restrict__ bv,
    bf16* __restrict__ Qp, bf16* __restrict__ Kp, bf16* __restrict__ VTg)
{
  __shared__ bf16 Al[3*BM*BK];   // 24 KB
  __shared__ bf16 Bl[3*BN*BK];   // 24 KB

  const unsigned hw = blockIdx.x + 8u*blockIdx.y + 256u*blockIdx.z;
  const unsigned wk = (hw & 7u)*96u + (hw >> 3);
  const int z  = (int)(wk >> 8);          // 0..2
  const unsigned rem = wk & 255u;
  const int by = (int)(rem >> 3), bx = (int)(rem & 7u);

  // z<2: A=X (rows=tokens m), B=W (rows=out-dims n)
  // z=2: A=Wv (rows=out-dims m), B=Xv (rows=tokens n)  -> C = V^T
  const bf16* A = z==0 ? Xq : z==1 ? Xk : Wv;
  const bf16* W = z==0 ? Wq : z==1 ? Wk : Xv;
  const float* bias = z==0 ? bq : z==1 ? bk : bv;
  const float scale = (z==0) ? QSCALE : 1.0f;
  const int m0 = (z < 2) ? by * BM : bx * BM;  // z=2: dims (8 blocks)
  const int n0 = (z < 2) ? bx * BN : by * BN;  // z=2: tokens (32 blocks)

  f32x4 acc[4][4] = {};
  gemm_core(A, W, m0, n0, Al, Bl, acc);

  const int lane = threadIdx.x & 63, wid = threadIdx.x >> 6;
  const int quad = lane >> 4, l16 = lane & 15;
  const int wm = wid >> 1, wn = wid & 1;

  if (z < 2) {
#pragma unroll
    for (int i = 0; i < 4; ++i) {
#pragma unroll
      for (int j = 0; j < 4; ++j) {
        int col = n0 + wn*64 + j*16 + l16;
        float bv2 = bias[col];
        bf16* outp = (z == 0) ? Qp : Kp;
#pragma unroll
        for (int r = 0; r < 4; ++r) {
          int row = m0 + wm*64 + i*16 + quad*4 + r;
          outp[(size_t)row*EMBED + col] = (bf16)((acc[i][j][r] + bv2) * scale);
        }
      }
    }
  } else {
    // V^T permuted store. token = tcol0 + j*16 + l16 (one 64-tile per wn).
    // pos = (j>>1)*32 + (l16>>2)*8 + (l16&3)*2 + (j&1): pack j=0,1 and j=2,3.
    const int tcol0 = n0 + wn*64;            // multiple of 64
    const int bb   = tcol0 >> 11;            // batch
    const int tile = (tcol0 & (SEQ-1)) >> 6; // 64-token tile index
    const int pbase = (l16 >> 2)*8 + (l16 & 3)*2;
#pragma unroll
    for (int i = 0; i < 4; ++i) {
      float4 bv4 = *(const float4*)&bias[m0 + wm*64 + i*16 + quad*4];
#pragma unroll
      for (int r = 0; r < 4; ++r) {
        int e = m0 + wm*64 + i*16 + quad*4 + r;
        int hh = e >> 6, dd = e & (HD-1);
        float bvr = (r==0) ? bv4.x : (r==1) ? bv4.y : (r==2) ? bv4.z : bv4.w;
        union { bf16 h[2]; u32 u; } p01, p23;
        p01.h[0] = (bf16)(acc[i][0][r] + bvr);
        p01.h[1] = (bf16)(acc[i][1][r] + bvr);
        p23.h[0] = (bf16)(acc[i][2][r] + bvr);
        p23.h[1] = (bf16)(acc[i][3][r] + bvr);
        size_t base = (((size_t)bb*NHEAD + hh)*HD + dd)*SEQ + tile*64;
        *(u32*)&VTg[base + pbase]      = p01.u;
        *(u32*)&VTg[base + 32 + pbase] = p23.u;
      }
    }
  }
}

// ---------------- O-projection: 128x64 tiles, fp32 out ----------------
// v7 (verified r7): depth-2 counted-vmcnt, triple-buffer, XCD swizzle.
__global__ __launch_bounds__(256) void oproj_kernel(
    const bf16* __restrict__ Ctx, const bf16* __restrict__ Wo,
    const float* __restrict__ bo, float* __restrict__ out)
{
  __shared__ bf16 Al[3*128*32];   // 24 KB
  __shared__ bf16 Bl[3*64*32];    // 12 KB
  const int tid  = threadIdx.x;
  const int lane = tid & 63, wid = tid >> 6;
  const int quad = lane >> 4, l16 = lane & 15;

  const unsigned hw = blockIdx.x + 16u*blockIdx.y;
  const unsigned wk = (hw & 7u)*64u + (hw >> 3);
  const int m0 = (int)(wk >> 4) * 128, n0 = (int)(wk & 15u) * 64;

  const int R = tid >> 2, Cc = tid & 3;
  const int gcol = (Cc ^ ((R >> 1) & 3)) * 8;
  const bf16* Ag = Ctx + (size_t)(m0 + R) * EMBED + gcol;
  const bf16* Bg = Wo  + (size_t)(n0 + R) * EMBED + gcol;
  bf16* AlW = Al + wid * 512;
  bf16* BlW = Bl + wid * 512;

#define OSTAGE(ki) do { \
    const int nb_ = (ki) % 3; const int k0_ = (ki) * BK; \
    g2l16(Ag + k0_,                    AlW + nb_*4096); \
    g2l16(Ag + (size_t)64*EMBED + k0_, AlW + nb_*4096 + 2048); \
    g2l16(Bg + k0_,                    BlW + nb_*2048); } while (0)

  OSTAGE(0);
  OSTAGE(1);                            // 6 loads in flight

  f32x4 acc[2][4] = {};
  for (int ki = 0; ki < NKI; ++ki) {
    if (ki < NKI - 1) asm volatile("s_waitcnt vmcnt(3)" ::: "memory");
    else              asm volatile("s_waitcnt vmcnt(0)" ::: "memory");
    __builtin_amdgcn_s_barrier();
    __builtin_amdgcn_sched_barrier(0);
    if (ki + 2 < NKI) OSTAGE(ki + 2);

    const bf16* Ac = Al + (ki % 3)*4096;
    const bf16* Bc = Bl + (ki % 3)*2048;
    bf16x8 af[2], bg[4];
#pragma unroll
    for (int u = 0; u < 2; ++u) {
      int ra = wid*32 + u*16 + l16;
      af[u] = *(const bf16x8*)(Ac + ra*32 + ((quad ^ ((ra>>1)&3))*8));
    }
#pragma unroll
    for (int j = 0; j < 4; ++j) {
      int rb = j*16 + l16;
      bg[j] = *(const bf16x8*)(Bc + rb*32 + ((quad ^ ((rb>>1)&3))*8));
    }
#pragma unroll
    for (int u = 0; u < 2; ++u)
#pragma unroll
      for (int j = 0; j < 4; ++j)
        acc[u][j] = MFMA(af[u], bg[j], acc[u][j]);
  }
#undef OSTAGE

#pragma unroll
  for (int u = 0; u < 2; ++u)
#pragma unroll
    for (int j = 0; j < 4; ++j) {
      int col = n0 + j*16 + l16;
      float bv = bo[col];
#pragma unroll
      for (int r = 0; r < 4; ++r) {
        int row = m0 + wid*32 + u*16 + quad*4 + r;
        out[(size_t)row*EMBED + col] = (acc[u][j][r] + bv);
      }
    }
}

// ---------------- flash attention, counted-vmcnt + XCD locality --------
// v10 (r12): r11 structure (mask-as-C-operand + setprio, both verified)
// with ALL LDS buffer indices made compile-time constant:
//  - V 3 -> 4 buffers ((kt-1)&3 / (kt+1)&3 instead of %3); LDS 40960 ->
//    49152 B (still 2 blocks/CU). Hazard: writer of buf (kt+1)&3 at iter
//    kt; previous reader was iter kt-2 (reads (kt-3)&3, same buf),
//    finished two barriers earlier — strictly safer than %3.
//  - #pragma unroll 4 on the kt loop (lcm of K-period 2, V-period 4;
//    NT=32 % 4 == 0): every instance has literal LDS bases, so the
//    compiler hoists the 8 fragment addresses/iter and drops the %3
//    integer math — targeting the 39% VALUBusy.
#define NT  (SEQ/64)

__global__ __launch_bounds__(512, 2) void attn_kernel(
    const bf16* __restrict__ Qp, const bf16* __restrict__ Kp, const bf16* __restrict__ VT,
    const int* __restrict__ pmask, bf16* __restrict__ Ctx)
{
  __shared__ __align__(16) bf16 SM[6*4096];   // K x2 @ [0,8K); V x4 @ [8K,24K) elems (48KB)

  // XCD-aware decode: wk = (hw%8)*64 + hw/8 (bijective, 512%8==0)
  const unsigned hw = blockIdx.x + 16u*blockIdx.y + 256u*blockIdx.z;
  const unsigned wkb = (hw & 7u)*64u + (hw >> 3);
  const int qt = (int)(wkb & 15u);
  const unsigned pair = wkb >> 4;            // 0..31
  const int h = (int)(pair & 15u), b = (int)(pair >> 4);

  const int tid = threadIdx.x, lane = tid & 63, wid = tid >> 6;
  const int quad = lane >> 4, l16 = lane & 15;
  const int w4 = wid & 3, h2 = wid >> 2;       // q-group, key-half
  const int qrow0 = qt*128 + w4*32;

  // Q fragments (MFMA B operand: col = query = l16), 2 q-subgroups x 2 dim-halves
  bf16x8 qf[2][2];
#pragma unroll
  for (int qg = 0; qg < 2; ++qg) {
    const size_t qoff = (size_t)(b*SEQ + qrow0 + qg*16 + l16)*EMBED + h*HD;
    qf[qg][0] = *(const bf16x8*)(Qp + qoff + quad*8);
    qf[qg][1] = *(const bf16x8*)(Qp + qoff + 32 + quad*8);
  }

  bf16 onev = (bf16)1.0f;
  bf16x8 ones = {onev, onev, onev, onev, onev, onev, onev, onev};
  const float NINF = -__builtin_huge_valf();

  const bf16* Kg  = Kp + (size_t)b*SEQ*EMBED + h*HD;
  const bf16* VTg = VT + (size_t)(b*NHEAD + h)*HD*SEQ;
  const int*  kmw = pmask + b*SEQ + h2*32 + quad*4;   // this wave's key-mask base

  const int R = tid >> 3;                 // 0..63 (key idx for K, dim for V)
  const int Cc = tid & 7;
  const int scol = (Cc ^ (R & 7)) * 8;    // swizzled source column

  f32x4 o[2][4] = {};                     // [qg][dim-group]
  f32x4 lacc[2] = {};
  bf16x8 pa[2] = {};                      // P fragments [qg], elem j = r*2 + kg

#define STAGE_K(kt, buf) g2l16(Kg + (size_t)((kt)*64 + R)*EMBED + scol, SM + (buf)*4096 + wid*512)
#define STAGE_V(kt, buf) g2l16(VTg + (size_t)R*SEQ + (kt)*64 + scol,    SM + 8192 + (buf)*4096 + wid*512)

  // prologue: masks(0) + tile(0) staging in flight
  int4 kq0 = *(const int4*)(kmw);
  int4 kq1 = *(const int4*)(kmw + 16);
  STAGE_K(0, 0);
  STAGE_V(0, 0);

#pragma unroll 4
  for (int kt = 0; kt < NT; ++kt) {
    // top-of-iteration rendezvous: my old loads done, then everyone's.
    asm volatile("s_waitcnt vmcnt(0)" ::: "memory");
    __builtin_amdgcn_s_barrier();
    __builtin_amdgcn_sched_barrier(0);

    // consume masks NOW -> additive -inf bias (MFMA C-operand trick).
    f32x4 mb0, mb1;
    mb0[0] = kq0.x ? 0.f : NINF; mb0[1] = kq0.y ? 0.f : NINF;
    mb0[2] = kq0.z ? 0.f : NINF; mb0[3] = kq0.w ? 0.f : NINF;
    mb1[0] = kq1.x ? 0.f : NINF; mb1[1] = kq1.y ? 0.f : NINF;
    mb1[2] = kq1.z ? 0.f : NINF; mb1[3] = kq1.w ? 0.f : NINF;
    __builtin_amdgcn_sched_barrier(0);

    // issue next-tile staging + masks: in flight across ALL of compute(kt)
    if (kt + 1 < NT) {
      kq0 = *(const int4*)(kmw + (kt+1)*64);
      kq1 = *(const int4*)(kmw + (kt+1)*64 + 16);
      STAGE_K(kt + 1, (kt + 1) & 1);
      STAGE_V(kt + 1, (kt + 1) & 3);
    }

    // ---- PV(kt-1): reads pa (then QK below overwrites it) ----
    if (kt > 0) {
      const bf16* Vc = SM + 8192 + ((kt - 1) & 3)*4096;
      __builtin_amdgcn_s_setprio(1);
      lacc[0] = MFMA(pa[0], ones, lacc[0]);
      lacc[1] = MFMA(pa[1], ones, lacc[1]);
#pragma unroll
      for (int t = 0; t < 4; ++t) {
        int rd = t*16 + l16, sd = rd & 7;
        bf16x8 vf = *(const bf16x8*)(Vc + rd*64 + (((h2*4 + quad) ^ sd)*8));
        o[0][t] = MFMA(pa[0], vf, o[0][t]);
        o[1][t] = MFMA(pa[1], vf, o[1][t]);
      }
      __builtin_amdgcn_s_setprio(0);
    }

    // ---- swapped QK^T(kt), mask pre-loaded in the accumulator ----
    const bf16* Kc = SM + (kt & 1)*4096;
#pragma unroll
    for (int kg = 0; kg < 2; ++kg) {
      int ra = h2*32 + kg*16 + l16, sa = ra & 7;
      bf16x8 kfa = *(const bf16x8*)(Kc + ra*64 + ((quad       ^ sa)*8));  // dims 0..31
      bf16x8 kfb = *(const bf16x8*)(Kc + ra*64 + (((quad + 4) ^ sa)*8));  // dims 32..63
#pragma unroll
      for (int qg = 0; qg < 2; ++qg) {
        f32x4 s = kg ? mb1 : mb0;       // masked keys start at -inf
        s = MFMA(kfa, qf[qg][0], s);
        s = MFMA(kfb, qf[qg][1], s);
        pa[qg][0 + kg] = (bf16)EXP2(s[0]);
        pa[qg][2 + kg] = (bf16)EXP2(s[1]);
        pa[qg][4 + kg] = (bf16)EXP2(s[2]);
        pa[qg][6 + kg] = (bf16)EXP2(s[3]);
      }
    }
    // no end-of-iteration barrier: next top's {vmcnt; s_barrier} covers it
  }

  // ---- epilogue PV(NT-1) ----
  {
    const bf16* Vc = SM + 8192 + ((NT - 1) & 3)*4096;
    lacc[0] = MFMA(pa[0], ones, lacc[0]);
    lacc[1] = MFMA(pa[1], ones, lacc[1]);
#pragma unroll
    for (int t = 0; t < 4; ++t) {
      int rd = t*16 + l16, sd = rd & 7;
      bf16x8 vf = *(const bf16x8*)(Vc + rd*64 + (((h2*4 + quad) ^ sd)*8));
      o[0][t] = MFMA(pa[0], vf, o[0][t]);
      o[1][t] = MFMA(pa[1], vf, o[1][t]);
    }
  }

  // ---- cross-half reduction via LDS (40960B <= 49152B) ----
  __syncthreads();                       // full drain + everyone done with K/V bufs
  f32x4* rp = (f32x4*)SM;
  const int idx = w4*64 + lane;          // 0..255
  if (h2 == 1) {
#pragma unroll
    for (int qg = 0; qg < 2; ++qg) {
#pragma unroll
      for (int t = 0; t < 4; ++t) rp[(qg*4 + t)*256 + idx] = o[qg][t];
      rp[2048 + qg*256 + idx] = lacc[qg];
    }
  }
  __syncthreads();
  if (h2 == 0) {
#pragma unroll
    for (int qg = 0; qg < 2; ++qg) {
      lacc[qg] += rp[2048 + qg*256 + idx];
#pragma unroll
      for (int t = 0; t < 4; ++t) o[qg][t] += rp[(qg*4 + t)*256 + idx];
    }
#pragma unroll
    for (int qg = 0; qg < 2; ++qg) {
      int4 qm = *(const int4*)(pmask + b*SEQ + qrow0 + qg*16 + quad*4);
      float inv[4];
      inv[0] = (qm.x && lacc[qg][0] > 0.f) ? 1.0f / lacc[qg][0] : 0.0f;
      inv[1] = (qm.y && lacc[qg][1] > 0.f) ? 1.0f / lacc[qg][1] : 0.0f;
      inv[2] = (qm.z && lacc[qg][2] > 0.f) ? 1.0f / lacc[qg][2] : 0.0f;
      inv[3] = (qm.w && lacc[qg][3] > 0.f) ? 1.0f / lacc[qg][3] : 0.0f;
#pragma unroll
      for (int t = 0; t < 4; ++t)
#pragma unroll
        for (int r = 0; r < 4; ++r) {
          int row = b*SEQ + qrow0 + qg*16 + quad*4 + r;
          Ctx[(size_t)row*EMBED + h*HD + t*16 + l16] = (bf16)(o[qg][t][r] * inv[r]);
        }
    }
  }
}

// ----------------------------------------------------------------------
extern "C" void kernel_launch(void* const* d_in, const int* in_sizes, int n_in,
                              void* d_out, int out_size, void* d_ws, size_t ws_size,
                              hipStream_t stream)
{
  const float* query = (const float*)d_in[0];
  const float* key   = (const float*)d_in[1];
  const float* value = (const float*)d_in[2];
  const int*   pm    = (const int*)d_in[3];
  const float* Wq = (const float*)d_in[4];
  const float* bq = (const float*)d_in[5];
  const float* Wk = (const float*)d_in[6];
  const float* bk = (const float*)d_in[7];
  const float* Wv = (const float*)d_in[8];
  const float* bv = (const float*)d_in[9];
  const float* Wo = (const float*)d_in[10];
  const float* bo = (const float*)d_in[11];
  float* out = (float*)d_out;

  const size_t SZ_X = (size_t)MROWS * EMBED;   // 4M elems
  const size_t SZ_W = (size_t)EMBED * EMBED;   // 1M elems

  bf16* p   = (bf16*)d_ws;
  bf16* Xq  = p; p += SZ_X;
  bf16* Xk  = p; p += SZ_X;
  bf16* Xv  = p; p += SZ_X;
  bf16* Wqb = p; p += SZ_W;
  bf16* Wkb = p; p += SZ_W;
  bf16* Wvb = p; p += SZ_W;
  bf16* Wob = p; p += SZ_W;
  bf16* Qp  = p; p += SZ_X;
  bf16* Kp  = p; p += SZ_X;
  bf16* VTg = p; p += SZ_X;   // V^T: [b][h][d][permuted s]
  bf16* Ctx = p; p += SZ_X;

  dim3 gc((unsigned)(SZX8/256), 7);   // one dispatch for all 7 casts
  cast_all<<<gc, 256, 0, stream>>>(query, key, value, Wq, Wk, Wv, Wo,
                                   Xq, Xk, Xv, Wqb, Wkb, Wvb, Wob);

  dim3 gq(EMBED/BN, MROWS/BM, 3);   // (8, 32, 3)
  qkv_kernel<<<gq, 256, 0, stream>>>(Xq, Xk, Xv, Wqb, Wkb, Wvb, bq, bk, bv, Qp, Kp, VTg);

  dim3 ga(SEQ/128, NHEAD, BATCH);   // (16, 16, 2) = 512 blocks, 2/CU
  attn_kernel<<<ga, 512, 0, stream>>>(Qp, Kp, VTg, pm, Ctx);

  dim3 gg(EMBED/64, MROWS/128);     // (16, 32) = 512 blocks
  oproj_kernel<<<gg, 256, 0, stream>>>(Ctx, Wob, bo, out);
}

// Round 13
// 211.815 us; speedup vs baseline: 1.0598x; 1.0598x over previous
//
#include <hip/hip_runtime.h>
#include <cstdint>
#include <cstddef>

#define EMBED 1024
#define NHEAD 16
#define HD    64
#define BATCH 2
#define SEQ   2048
#define MROWS (BATCH*SEQ)   // 4096
#define QSCALE 0.1803368801111137f   // log2(e)/8

typedef __bf16 bf16;
typedef __bf16 bf16x8 __attribute__((ext_vector_type(8)));
typedef float  f32x4  __attribute__((ext_vector_type(4)));
typedef unsigned int u32;

#if __has_builtin(__builtin_amdgcn_exp2f)
#define EXP2(x) __builtin_amdgcn_exp2f(x)
#else
#define EXP2(x) exp2f(x)
#endif

typedef const u32 __attribute__((address_space(1)))* gp_t;
typedef u32 __attribute__((address_space(3)))* lp_t;

// async global->LDS, 16B/lane; LDS dest = wave-uniform base + lane*16
__device__ __forceinline__ void g2l16(const void* g, void* l) {
  __builtin_amdgcn_global_load_lds((gp_t)(uintptr_t)g, (lp_t)(u32)(uintptr_t)l, 16, 0, 0);
}

#define MFMA(a, b, c) __builtin_amdgcn_mfma_f32_16x16x32_bf16((a), (b), (c), 0, 0, 0)

// ---------------- all casts fp32 -> bf16, one dispatch ----------------
#define SZX8 ((MROWS*EMBED)/8)   // 524288
#define SZW8 ((EMBED*EMBED)/8)   // 131072

__global__ void cast_all(const float* __restrict__ q, const float* __restrict__ k,
                         const float* __restrict__ v, const float* __restrict__ wq,
                         const float* __restrict__ wk, const float* __restrict__ wv,
                         const float* __restrict__ wo,
                         bf16* xq, bf16* xk, bf16* xv,
                         bf16* wqb, bf16* wkb, bf16* wvb, bf16* wob) {
  int z = blockIdx.y;
  const float* in; bf16* out;
  switch (z) {
    case 0: in = q;  out = xq;  break;
    case 1: in = k;  out = xk;  break;
    case 2: in = v;  out = xv;  break;
    case 3: in = wq; out = wqb; break;
    case 4: in = wk; out = wkb; break;
    case 5: in = wv; out = wvb; break;
    default: in = wo; out = wob; break;
  }
  int n8 = (z < 3) ? SZX8 : SZW8;
  int i = blockIdx.x * blockDim.x + threadIdx.x;
  if (i >= n8) return;
  const float4* p = (const float4*)in;
  float4 a = p[2*i], b = p[2*i+1];
  union { bf16 h[8]; uint4 u; } r;
  r.h[0] = (bf16)a.x; r.h[1] = (bf16)a.y; r.h[2] = (bf16)a.z; r.h[3] = (bf16)a.w;
  r.h[4] = (bf16)b.x; r.h[5] = (bf16)b.y; r.h[6] = (bf16)b.z; r.h[7] = (bf16)b.w;
  ((uint4*)out)[i] = r.u;
}

// ---------------- GEMM core 128x128: C = A @ B^T ----------------------
// v7 (verified r7): DEPTH-2 counted-vmcnt pipeline, triple-buffer LDS.
#define BM 128
#define BN 128
#define BK 32
#define NKI (EMBED/BK)   // 32

__device__ __forceinline__ void gemm_core(
    const bf16* __restrict__ A, const bf16* __restrict__ W,
    int m0, int n0, bf16* Al, bf16* Bl, f32x4 (&acc)[4][4])
{
  const int tid  = threadIdx.x;
  const int lane = tid & 63, wid = tid >> 6;
  const int quad = lane >> 4, l16 = lane & 15;
  const int wm = wid >> 1, wn = wid & 1;

  const int R = tid >> 2, Cc = tid & 3;
  const int gcol = (Cc ^ ((R >> 1) & 3)) * 8;          // swizzled source column
  const bf16* Ag = A + (size_t)(m0 + R) * EMBED + gcol;
  const bf16* Bg = W + (size_t)(n0 + R) * EMBED + gcol;
  bf16* AlW = Al + wid * 512;                          // wave's 1KB chunk
  bf16* BlW = Bl + wid * 512;

#define GSTAGE(ki) do { \
    const int nb_ = (ki) % 3; const int k0_ = (ki) * BK; \
    g2l16(Ag + k0_,                    AlW + nb_*4096); \
    g2l16(Ag + (size_t)64*EMBED + k0_, AlW + nb_*4096 + 2048); \
    g2l16(Bg + k0_,                    BlW + nb_*4096); \
    g2l16(Bg + (size_t)64*EMBED + k0_, BlW + nb_*4096 + 2048); } while (0)

  GSTAGE(0);
  GSTAGE(1);                            // 8 loads in flight

  for (int ki = 0; ki < NKI; ++ki) {
    if (ki < NKI - 1) asm volatile("s_waitcnt vmcnt(4)" ::: "memory");
    else              asm volatile("s_waitcnt vmcnt(0)" ::: "memory");
    __builtin_amdgcn_s_barrier();
    __builtin_amdgcn_sched_barrier(0);
    if (ki + 2 < NKI) GSTAGE(ki + 2);   // in flight across 2 compute phases

    const bf16* Ac = Al + (ki % 3)*4096;
    const bf16* Bc = Bl + (ki % 3)*4096;
    bf16x8 af[4], bg[4];
#pragma unroll
    for (int i = 0; i < 4; ++i) {
      int ra = wm*64 + i*16 + l16;
      af[i] = *(const bf16x8*)(Ac + ra*32 + ((quad ^ ((ra>>1)&3))*8));
      int rb = wn*64 + i*16 + l16;
      bg[i] = *(const bf16x8*)(Bc + rb*32 + ((quad ^ ((rb>>1)&3))*8));
    }
#pragma unroll
    for (int i = 0; i < 4; ++i)
#pragma unroll
      for (int j = 0; j < 4; ++j)
        acc[i][j] = MFMA(af[i], bg[j], acc[i][j]);
    // no end-of-iteration barrier: next top's {vmcnt; s_barrier} covers it
  }
#undef GSTAGE
}

// QKV fused: work-index selects {Q,K,V}. Q scaled by log2(e)/8.
// z==2 computes V^T DIRECTLY: C[dim][token] = Wv @ Xv^T, stored permuted
// per 64-token tile for the key-half-split attn PV A-fragment:
//   token loc = g*16 + quad*4 + r  ->  pos = (g>>1)*32 + quad*8 + r*2 + (g&1)
// XCD swizzle (verified r7): hw%8 = XCD; XCD k owns contiguous range.
__global__ __launch_bounds__(256) void qkv_kernel(
    const bf16* __restrict__ Xq, const bf16* __restrict__ Xk, const bf16* __restrict__ Xv,
    const bf16* __restrict__ Wq, const bf16* __restrict__ Wk, const bf16* __restrict__ Wv,
    const float* __restrict__ bq, const float* __restrict__ bk, const float* __restrict__ bv,
    bf16* __restrict__ Qp, bf16* __restrict__ Kp, bf16* __restrict__ VTg)
{
  __shared__ bf16 Al[3*BM*BK];   // 24 KB
  __shared__ bf16 Bl[3*BN*BK];   // 24 KB

  const unsigned hw = blockIdx.x + 8u*blockIdx.y + 256u*blockIdx.z;
  const unsigned wk = (hw & 7u)*96u + (hw >> 3);
  const int z  = (int)(wk >> 8);          // 0..2
  const unsigned rem = wk & 255u;
  const int by = (int)(rem >> 3), bx = (int)(rem & 7u);

  // z<2: A=X (rows=tokens m), B=W (rows=out-dims n)
  // z=2: A=Wv (rows=out-dims m), B=Xv (rows=tokens n)  -> C = V^T
  const bf16* A = z==0 ? Xq : z==1 ? Xk : Wv;
  const bf16* W = z==0 ? Wq : z==1 ? Wk : Xv;
  const float* bias = z==0 ? bq : z==1 ? bk : bv;
  const float scale = (z==0) ? QSCALE : 1.0f;
  const int m0 = (z < 2) ? by * BM : bx * BM;  // z=2: dims (8 blocks)
  const int n0 = (z < 2) ? bx * BN : by * BN;  // z=2: tokens (32 blocks)

  f32x4 acc[4][4] = {};
  gemm_core(A, W, m0, n0, Al, Bl, acc);

  const int lane = threadIdx.x & 63, wid = threadIdx.x >> 6;
  const int quad = lane >> 4, l16 = lane & 15;
  const int wm = wid >> 1, wn = wid & 1;

  if (z < 2) {
#pragma unroll
    for (int i = 0; i < 4; ++i) {
#pragma unroll
      for (int j = 0; j < 4; ++j) {
        int col = n0 + wn*64 + j*16 + l16;
        float bv2 = bias[col];
        bf16* outp = (z == 0) ? Qp : Kp;
#pragma unroll
        for (int r = 0; r < 4; ++r) {
          int row = m0 + wm*64 + i*16 + quad*4 + r;
          outp[(size_t)row*EMBED + col] = (bf16)((acc[i][j][r] + bv2) * scale);
        }
      }
    }
  } else {
    // V^T permuted store. token = tcol0 + j*16 + l16 (one 64-tile per wn).
    // pos = (j>>1)*32 + (l16>>2)*8 + (l16&3)*2 + (j&1): pack j=0,1 and j=2,3.
    const int tcol0 = n0 + wn*64;            // multiple of 64
    const int bb   = tcol0 >> 11;            // batch
    const int tile = (tcol0 & (SEQ-1)) >> 6; // 64-token tile index
    const int pbase = (l16 >> 2)*8 + (l16 & 3)*2;
#pragma unroll
    for (int i = 0; i < 4; ++i) {
      float4 bv4 = *(const float4*)&bias[m0 + wm*64 + i*16 + quad*4];
#pragma unroll
      for (int r = 0; r < 4; ++r) {
        int e = m0 + wm*64 + i*16 + quad*4 + r;
        int hh = e >> 6, dd = e & (HD-1);
        float bvr = (r==0) ? bv4.x : (r==1) ? bv4.y : (r==2) ? bv4.z : bv4.w;
        union { bf16 h[2]; u32 u; } p01, p23;
        p01.h[0] = (bf16)(acc[i][0][r] + bvr);
        p01.h[1] = (bf16)(acc[i][1][r] + bvr);
        p23.h[0] = (bf16)(acc[i][2][r] + bvr);
        p23.h[1] = (bf16)(acc[i][3][r] + bvr);
        size_t base = (((size_t)bb*NHEAD + hh)*HD + dd)*SEQ + tile*64;
        *(u32*)&VTg[base + pbase]      = p01.u;
        *(u32*)&VTg[base + 32 + pbase] = p23.u;
      }
    }
  }
}

// ---------------- O-projection: 128x64 tiles, fp32 out ----------------
// v7 (verified r7): depth-2 counted-vmcnt, triple-buffer, XCD swizzle.
__global__ __launch_bounds__(256) void oproj_kernel(
    const bf16* __restrict__ Ctx, const bf16* __restrict__ Wo,
    const float* __restrict__ bo, float* __restrict__ out)
{
  __shared__ bf16 Al[3*128*32];   // 24 KB
  __shared__ bf16 Bl[3*64*32];    // 12 KB
  const int tid  = threadIdx.x;
  const int lane = tid & 63, wid = tid >> 6;
  const int quad = lane >> 4, l16 = lane & 15;

  const unsigned hw = blockIdx.x + 16u*blockIdx.y;
  const unsigned wk = (hw & 7u)*64u + (hw >> 3);
  const int m0 = (int)(wk >> 4) * 128, n0 = (int)(wk & 15u) * 64;

  const int R = tid >> 2, Cc = tid & 3;
  const int gcol = (Cc ^ ((R >> 1) & 3)) * 8;
  const bf16* Ag = Ctx + (size_t)(m0 + R) * EMBED + gcol;
  const bf16* Bg = Wo  + (size_t)(n0 + R) * EMBED + gcol;
  bf16* AlW = Al + wid * 512;
  bf16* BlW = Bl + wid * 512;

#define OSTAGE(ki) do { \
    const int nb_ = (ki) % 3; const int k0_ = (ki) * BK; \
    g2l16(Ag + k0_,                    AlW + nb_*4096); \
    g2l16(Ag + (size_t)64*EMBED + k0_, AlW + nb_*4096 + 2048); \
    g2l16(Bg + k0_,                    BlW + nb_*2048); } while (0)

  OSTAGE(0);
  OSTAGE(1);                            // 6 loads in flight

  f32x4 acc[2][4] = {};
  for (int ki = 0; ki < NKI; ++ki) {
    if (ki < NKI - 1) asm volatile("s_waitcnt vmcnt(3)" ::: "memory");
    else              asm volatile("s_waitcnt vmcnt(0)" ::: "memory");
    __builtin_amdgcn_s_barrier();
    __builtin_amdgcn_sched_barrier(0);
    if (ki + 2 < NKI) OSTAGE(ki + 2);

    const bf16* Ac = Al + (ki % 3)*4096;
    const bf16* Bc = Bl + (ki % 3)*2048;
    bf16x8 af[2], bg[4];
#pragma unroll
    for (int u = 0; u < 2; ++u) {
      int ra = wid*32 + u*16 + l16;
      af[u] = *(const bf16x8*)(Ac + ra*32 + ((quad ^ ((ra>>1)&3))*8));
    }
#pragma unroll
    for (int j = 0; j < 4; ++j) {
      int rb = j*16 + l16;
      bg[j] = *(const bf16x8*)(Bc + rb*32 + ((quad ^ ((rb>>1)&3))*8));
    }
#pragma unroll
    for (int u = 0; u < 2; ++u)
#pragma unroll
      for (int j = 0; j < 4; ++j)
        acc[u][j] = MFMA(af[u], bg[j], acc[u][j]);
  }
#undef OSTAGE

#pragma unroll
  for (int u = 0; u < 2; ++u)
#pragma unroll
    for (int j = 0; j < 4; ++j) {
      int col = n0 + j*16 + l16;
      float bv = bo[col];
#pragma unroll
      for (int r = 0; r < 4; ++r) {
        int row = m0 + wid*32 + u*16 + quad*4 + r;
        out[(size_t)row*EMBED + col] = (acc[u][j][r] + bv);
      }
    }
}

// ---------------- flash attention, counted-vmcnt + XCD locality --------
// v9 (r13 = exact r11 revert; r12's unroll-4 + V&3 regressed: VGPR 56->72,
// occupancy 30->20.5%, latency re-exposed — Guideline-6 failure).
// Structure: 8 waves = 4 q-groups x 2 key-halves, swapped QK^T, register
// P; depth-1 counted-vmcnt schedule (top {vmcnt(0); s_barrier}, staging
// issued after the barrier); XCD-aware block mapping (r9, FETCH 12.4MB);
// mask folded into the MFMA C-operand (s = K*Q + (mask?0:-inf)); T5
// setprio around the PV MFMA cluster. Verified attn 47.7us @ r11.
#define NT  (SEQ/64)

__global__ __launch_bounds__(512, 2) void attn_kernel(
    const bf16* __restrict__ Qp, const bf16* __restrict__ Kp, const bf16* __restrict__ VT,
    const int* __restrict__ pmask, bf16* __restrict__ Ctx)
{
  __shared__ __align__(16) bf16 SM[5*4096];   // [0,8K): K x2; [8K,20K): V x3 (elems)

  // XCD-aware decode: wk = (hw%8)*64 + hw/8 (bijective, 512%8==0)
  const unsigned hw = blockIdx.x + 16u*blockIdx.y + 256u*blockIdx.z;
  const unsigned wkb = (hw & 7u)*64u + (hw >> 3);
  const int qt = (int)(wkb & 15u);
  const unsigned pair = wkb >> 4;            // 0..31
  const int h = (int)(pair & 15u), b = (int)(pair >> 4);

  const int tid = threadIdx.x, lane = tid & 63, wid = tid >> 6;
  const int quad = lane >> 4, l16 = lane & 15;
  const int w4 = wid & 3, h2 = wid >> 2;       // q-group, key-half
  const int qrow0 = qt*128 + w4*32;

  // Q fragments (MFMA B operand: col = query = l16), 2 q-subgroups x 2 dim-halves
  bf16x8 qf[2][2];
#pragma unroll
  for (int qg = 0; qg < 2; ++qg) {
    const size_t qoff = (size_t)(b*SEQ + qrow0 + qg*16 + l16)*EMBED + h*HD;
    qf[qg][0] = *(const bf16x8*)(Qp + qoff + quad*8);
    qf[qg][1] = *(const bf16x8*)(Qp + qoff + 32 + quad*8);
  }

  bf16 onev = (bf16)1.0f;
  bf16x8 ones = {onev, onev, onev, onev, onev, onev, onev, onev};
  const float NINF = -__builtin_huge_valf();

  const bf16* Kg  = Kp + (size_t)b*SEQ*EMBED + h*HD;
  const bf16* VTg = VT + (size_t)(b*NHEAD + h)*HD*SEQ;
  const int*  kmw = pmask + b*SEQ + h2*32 + quad*4;   // this wave's key-mask base

  const int R = tid >> 3;                 // 0..63 (key idx for K, dim for V)
  const int Cc = tid & 7;
  const int scol = (Cc ^ (R & 7)) * 8;    // swizzled source column

  f32x4 o[2][4] = {};                     // [qg][dim-group]
  f32x4 lacc[2] = {};
  bf16x8 pa[2] = {};                      // P fragments [qg], elem j = r*2 + kg

#define STAGE_K(kt, buf) g2l16(Kg + (size_t)((kt)*64 + R)*EMBED + scol, SM + (buf)*4096 + wid*512)
#define STAGE_V(kt, buf) g2l16(VTg + (size_t)R*SEQ + (kt)*64 + scol,    SM + 8192 + (buf)*4096 + wid*512)

  // prologue: masks(0) + tile(0) staging in flight
  int4 kq0 = *(const int4*)(kmw);
  int4 kq1 = *(const int4*)(kmw + 16);
  STAGE_K(0, 0);
  STAGE_V(0, 0);

  for (int kt = 0; kt < NT; ++kt) {
    // top-of-iteration rendezvous: my old loads done, then everyone's.
    asm volatile("s_waitcnt vmcnt(0)" ::: "memory");
    __builtin_amdgcn_s_barrier();
    __builtin_amdgcn_sched_barrier(0);

    // consume masks NOW -> additive -inf bias (MFMA C-operand trick).
    // (auto-waitcnt for kq lands before the new issues -> cannot drain
    // the fresh stages)
    f32x4 mb0, mb1;
    mb0[0] = kq0.x ? 0.f : NINF; mb0[1] = kq0.y ? 0.f : NINF;
    mb0[2] = kq0.z ? 0.f : NINF; mb0[3] = kq0.w ? 0.f : NINF;
    mb1[0] = kq1.x ? 0.f : NINF; mb1[1] = kq1.y ? 0.f : NINF;
    mb1[2] = kq1.z ? 0.f : NINF; mb1[3] = kq1.w ? 0.f : NINF;
    __builtin_amdgcn_sched_barrier(0);

    // issue next-tile staging + masks: in flight across ALL of compute(kt)
    if (kt + 1 < NT) {
      kq0 = *(const int4*)(kmw + (kt+1)*64);
      kq1 = *(const int4*)(kmw + (kt+1)*64 + 16);
      STAGE_K(kt + 1, (kt + 1) & 1);
      STAGE_V(kt + 1, (kt + 1) % 3);
    }

    // ---- PV(kt-1): reads pa (then QK below overwrites it) ----
    if (kt > 0) {
      const bf16* Vc = SM + 8192 + ((kt - 1) % 3)*4096;
      __builtin_amdgcn_s_setprio(1);
      lacc[0] = MFMA(pa[0], ones, lacc[0]);
      lacc[1] = MFMA(pa[1], ones, lacc[1]);
#pragma unroll
      for (int t = 0; t < 4; ++t) {
        int rd = t*16 + l16, sd = rd & 7;
        bf16x8 vf = *(const bf16x8*)(Vc + rd*64 + (((h2*4 + quad) ^ sd)*8));
        o[0][t] = MFMA(pa[0], vf, o[0][t]);
        o[1][t] = MFMA(pa[1], vf, o[1][t]);
      }
      __builtin_amdgcn_s_setprio(0);
    }

    // ---- swapped QK^T(kt), mask pre-loaded in the accumulator ----
    const bf16* Kc = SM + (kt & 1)*4096;
#pragma unroll
    for (int kg = 0; kg < 2; ++kg) {
      int ra = h2*32 + kg*16 + l16, sa = ra & 7;
      bf16x8 kfa = *(const bf16x8*)(Kc + ra*64 + ((quad       ^ sa)*8));  // dims 0..31
      bf16x8 kfb = *(const bf16x8*)(Kc + ra*64 + (((quad + 4) ^ sa)*8));  // dims 32..63
#pragma unroll
      for (int qg = 0; qg < 2; ++qg) {
        f32x4 s = kg ? mb1 : mb0;       // masked keys start at -inf
        s = MFMA(kfa, qf[qg][0], s);
        s = MFMA(kfb, qf[qg][1], s);
        pa[qg][0 + kg] = (bf16)EXP2(s[0]);
        pa[qg][2 + kg] = (bf16)EXP2(s[1]);
        pa[qg][4 + kg] = (bf16)EXP2(s[2]);
        pa[qg][6 + kg] = (bf16)EXP2(s[3]);
      }
    }
    // no end-of-iteration barrier: next top's {vmcnt; s_barrier} covers it
  }

  // ---- epilogue PV(NT-1) ----
  {
    const bf16* Vc = SM + 8192 + ((NT - 1) % 3)*4096;
    lacc[0] = MFMA(pa[0], ones, lacc[0]);
    lacc[1] = MFMA(pa[1], ones, lacc[1]);
#pragma unroll
    for (int t = 0; t < 4; ++t) {
      int rd = t*16 + l16, sd = rd & 7;
      bf16x8 vf = *(const bf16x8*)(Vc + rd*64 + (((h2*4 + quad) ^ sd)*8));
      o[0][t] = MFMA(pa[0], vf, o[0][t]);
      o[1][t] = MFMA(pa[1], vf, o[1][t]);
    }
  }

  // ---- cross-half reduction via LDS (exactly 40960B) ----
  __syncthreads();                       // full drain + everyone done with K/V bufs
  f32x4* rp = (f32x4*)SM;
  const int idx = w4*64 + lane;          // 0..255
  if (h2 == 1) {
#pragma unroll
    for (int qg = 0; qg < 2; ++qg) {
#pragma unroll
      for (int t = 0; t < 4; ++t) rp[(qg*4 + t)*256 + idx] = o[qg][t];
      rp[2048 + qg*256 + idx] = lacc[qg];
    }
  }
  __syncthreads();
  if (h2 == 0) {
#pragma unroll
    for (int qg = 0; qg < 2; ++qg) {
      lacc[qg] += rp[2048 + qg*256 + idx];
#pragma unroll
      for (int t = 0; t < 4; ++t) o[qg][t] += rp[(qg*4 + t)*256 + idx];
    }
#pragma unroll
    for (int qg = 0; qg < 2; ++qg) {
      int4 qm = *(const int4*)(pmask + b*SEQ + qrow0 + qg*16 + quad*4);
      float inv[4];
      inv[0] = (qm.x && lacc[qg][0] > 0.f) ? 1.0f / lacc[qg][0] : 0.0f;
      inv[1] = (qm.y && lacc[qg][1] > 0.f) ? 1.0f / lacc[qg][1] : 0.0f;
      inv[2] = (qm.z && lacc[qg][2] > 0.f) ? 1.0f / lacc[qg][2] : 0.0f;
      inv[3] = (qm.w && lacc[qg][3] > 0.f) ? 1.0f / lacc[qg][3] : 0.0f;
#pragma unroll
      for (int t = 0; t < 4; ++t)
#pragma unroll
        for (int r = 0; r < 4; ++r) {
          int row = b*SEQ + qrow0 + qg*16 + quad*4 + r;
          Ctx[(size_t)row*EMBED + h*HD + t*16 + l16] = (bf16)(o[qg][t][r] * inv[r]);
        }
    }
  }
}

// ----------------------------------------------------------------------
extern "C" void kernel_launch(void* const* d_in, const int* in_sizes, int n_in,
                              void* d_out, int out_size, void* d_ws, size_t ws_size,
                              hipStream_t stream)
{
  const float* query = (const float*)d_in[0];
  const float* key   = (const float*)d_in[1];
  const float* value = (const float*)d_in[2];
  const int*   pm    = (const int*)d_in[3];
  const float* Wq = (const float*)d_in[4];
  const float* bq = (const float*)d_in[5];
  const float* Wk = (const float*)d_in[6];
  const float* bk = (const float*)d_in[7];
  const float* Wv = (const float*)d_in[8];
  const float* bv = (const float*)d_in[9];
  const float* Wo = (const float*)d_in[10];
  const float* bo = (const float*)d_in[11];
  float* out = (float*)d_out;

  const size_t SZ_X = (size_t)MROWS * EMBED;   // 4M elems
  const size_t SZ_W = (size_t)EMBED * EMBED;   // 1M elems

  bf16* p   = (bf16*)d_ws;
  bf16* Xq  = p; p += SZ_X;
  bf16* Xk  = p; p += SZ_X;
  bf16* Xv  = p; p += SZ_X;
  bf16* Wqb = p; p += SZ_W;
  bf16* Wkb = p; p += SZ_W;
  bf16* Wvb = p; p += SZ_W;
  bf16* Wob = p; p += SZ_W;
  bf16* Qp  = p; p += SZ_X;
  bf16* Kp  = p; p += SZ_X;
  bf16* VTg = p; p += SZ_X;   // V^T: [b][h][d][permuted s]
  bf16* Ctx = p; p += SZ_X;

  dim3 gc((unsigned)(SZX8/256), 7);   // one dispatch for all 7 casts
  cast_all<<<gc, 256, 0, stream>>>(query, key, value, Wq, Wk, Wv, Wo,
                                   Xq, Xk, Xv, Wqb, Wkb, Wvb, Wob);

  dim3 gq(EMBED/BN, MROWS/BM, 3);   // (8, 32, 3)
  qkv_kernel<<<gq, 256, 0, stream>>>(Xq, Xk, Xv, Wqb, Wkb, Wvb, bq, bk, bv, Qp, Kp, VTg);

  dim3 ga(SEQ/128, NHEAD, BATCH);   // (16, 16, 2) = 512 blocks, 2/CU
  attn_kernel<<<ga, 512, 0, stream>>>(Qp, Kp, VTg, pm, Ctx);

  dim3 gg(EMBED/64, MROWS/128);     // (16, 32) = 512 blocks
  oproj_kernel<<<gg, 256, 0, stream>>>(Ctx, Wob, bo, out);
}